// Round 5
// baseline (392.347 us; speedup 1.0000x reference)
//
#include <hip/hip_runtime.h>

// ---------------------------------------------------------------------------
// MultiHeadsAttention: X[4,2048,1024] -> ctx[4,2048,1024], q[4,16,2048,64],
// k[4,16,2048,64] (q,k post-RoPE). fp32 in/out, bf16 MFMA internally.
// Round 13: qkv_gemm was latency-bound (MfmaUtil 17 / VALU 16 / HBM 31 /
// occ 28 — nothing saturated) with FETCH 161MB vs ~54MB ideal: consecutive
// n-blocks sharing an A-tile round-robin across 8 XCDs -> 8x A re-fetch,
// staging loads miss L2 (~900cy) and the loop drains them cold at the
// barrier. Fix: (1) T1 chunked XCD swizzle (new=(lin&7)*192+lin>>3,
// bijective since 1536%8==0) -> A-tile reused 8x inside one XCD's L2,
// B (2MB/z) L2-resident; (2) re-apply R11 issue-before-compute dbuf — with
// L2-hit latency ~250cy the ~176cy compute phase now actually covers it
// (R11 alone was null because 900cy HBM misses dwarfed the compute).
// attn frozen (R12-measured 124us).
// ---------------------------------------------------------------------------

#define B_  4
#define S_  2048
#define H_  16
#define D_  64
#define HID 1024
#define M_  (B_ * S_)          // 8192

typedef __attribute__((ext_vector_type(8))) short    bf16x8;
typedef __attribute__((ext_vector_type(4))) float    f32x4;
typedef __attribute__((ext_vector_type(4))) unsigned short u16x4;
typedef __attribute__((ext_vector_type(8))) unsigned short u16x8;
typedef __attribute__((ext_vector_type(2))) unsigned u32x2;

__device__ __forceinline__ unsigned short f2bf(float f) {
    union { float f; unsigned u; } v; v.f = f;
    unsigned r = v.u + 0x7fffu + ((v.u >> 16) & 1u);
    return (unsigned short)(r >> 16);
}

__device__ __forceinline__ void async16(const unsigned short* g, unsigned short* l) {
    __builtin_amdgcn_global_load_lds(
        (const __attribute__((address_space(1))) void*)g,
        (__attribute__((address_space(3))) void*)l, 16, 0, 0);
}

__device__ __forceinline__ float fast_exp2(float x) {
    float r;
    asm("v_exp_f32 %0, %1" : "=v"(r) : "v"(x));
    return r;
}

// ---------------------------------------------------------------------------
// Kernel 0: RoPE tables -> d_out ctx region (overwritten later by attn).
// ---------------------------------------------------------------------------
__global__ __launch_bounds__(256) void rope_table_kernel(float* __restrict__ tab)
{
    int i = blockIdx.x * 256 + threadIdx.x;     // 0 .. 131071
    int s = i >> 6, d = i & 63;
    const float NEG_LN1E4_32 = -0.28782313662425576f;  // -ln(10000)/32
    float freq = __expf(NEG_LN1E4_32 * (float)(d >> 1));
    float ang = (float)s * freq;
    tab[i]          = cosf(ang);
    tab[131072 + i] = sinf(ang);
}

// ---------------------------------------------------------------------------
// Kernel 1: cast X fp32 -> bf16
// ---------------------------------------------------------------------------
__global__ __launch_bounds__(256) void cast_x_kernel(
    const float* __restrict__ X, unsigned short* __restrict__ Xb)
{
    int i = (blockIdx.x * 256 + threadIdx.x) * 4;
    float4 v = *(const float4*)(X + i);
    u16x4 o;
    o[0] = f2bf(v.x); o[1] = f2bf(v.y); o[2] = f2bf(v.z); o[3] = f2bf(v.w);
    *(u16x4*)(Xb + i) = o;
}

// ---------------------------------------------------------------------------
// Kernel 2: transpose+cast W[k][n] fp32 -> Wt[n][k] bf16  (z selects q/k/v)
// ---------------------------------------------------------------------------
__global__ __launch_bounds__(256) void cast_wt_kernel(
    const float* __restrict__ Wq, const float* __restrict__ Wk,
    const float* __restrict__ Wv, unsigned short* __restrict__ Wt)
{
    __shared__ float tile[64][65];
    int z = blockIdx.z;
    const float* W = (z == 0) ? Wq : ((z == 1) ? Wk : Wv);
    unsigned short* out = Wt + (size_t)z * HID * HID;
    int n0 = blockIdx.x * 64, k0 = blockIdx.y * 64;
    int tx = threadIdx.x & 63, ty0 = threadIdx.x >> 6;
#pragma unroll
    for (int i = 0; i < 16; i++) {
        int ty = ty0 * 16 + i;
        tile[ty][tx] = W[(size_t)(k0 + ty) * HID + n0 + tx];
    }
    __syncthreads();
#pragma unroll
    for (int i = 0; i < 16; i++) {
        int ty = ty0 * 16 + i;
        out[(size_t)(n0 + ty) * HID + k0 + tx] = f2bf(tile[tx][ty]);
    }
}

// ---------------------------------------------------------------------------
// Kernel 3: QKV GEMM, 128x128 tile, BK=32, global_load_lds staging,
// 4 waves each 64x64 (4x4 frags of 16x16x32 MFMA). Bias + table-RoPE epilogue.
// Round 13: chunked XCD swizzle + issue-before-compute LDS double-buffer.
// ---------------------------------------------------------------------------
#define BM 128
#define BN 128
#define BKQ 32

__global__ __launch_bounds__(256) void qkv_gemm_kernel(
    const unsigned short* __restrict__ Xb, const unsigned short* __restrict__ Wt,
    const float* __restrict__ bq, const float* __restrict__ bk,
    const float* __restrict__ bv,
    const float* __restrict__ cosT, const float* __restrict__ sinT,
    float* out,
    unsigned short* __restrict__ Qb, unsigned short* __restrict__ Kb,
    unsigned short* __restrict__ Vb)
{
    __shared__ unsigned short As[2][BM * BKQ];   // 2 x 8 KB
    __shared__ unsigned short Bs[2][BN * BKQ];   // 2 x 8 KB

    const size_t Q_OFF = (size_t)B_ * S_ * HID;
    const size_t K_OFF = 2 * Q_OFF;

    // chunked XCD swizzle: lin = x + 8*(y + 64*z); 1536 blocks, 8 XCDs,
    // chunk = 192 consecutive works per XCD, x-fastest within chunk so the
    // 8 n-blocks sharing an A-tile run on ONE XCD (A-tile L2-reuse; B
    // (2MB/z) stays L2-resident).
    int lin = blockIdx.x + 8 * (blockIdx.y + 64 * blockIdx.z);
    int nl  = (lin & 7) * 192 + (lin >> 3);
    int z   = nl >> 9;
    int rem = nl & 511;
    int n0 = (rem & 7) * BN, m0 = (rem >> 3) * BM;

    const unsigned short* W = Wt + (size_t)z * HID * HID;
    const float* bias = (z == 0) ? bq : ((z == 1) ? bk : bv);

    int tid = threadIdx.x;
    int wave = tid >> 6, lane = tid & 63;
    int quad = lane >> 4, l15 = lane & 15;
    int wm = (wave >> 1) * 64;
    int wn = (wave & 1) * 64;

    const unsigned short* Ag = Xb + (size_t)m0 * HID;
    const unsigned short* Bg = W  + (size_t)n0 * HID;

    int e0 = tid, e1 = 256 + tid;
    int r0 = e0 >> 2, c0 = (e0 & 3) * 8;
    int r1 = e1 >> 2, c1 = (e1 & 3) * 8;

    f32x4 acc[4][4] = {};

    // prologue: stage K-tile 0 into buf 0
    async16(Ag + (size_t)r0 * HID + c0, &As[0][e0 * 8]);
    async16(Ag + (size_t)r1 * HID + c1, &As[0][e1 * 8]);
    async16(Bg + (size_t)r0 * HID + c0, &Bs[0][e0 * 8]);
    async16(Bg + (size_t)r1 * HID + c1, &Bs[0][e1 * 8]);
    __syncthreads();

    int cur = 0;
    for (int k0 = 0; k0 < HID; k0 += BKQ) {
        // issue next tile's loads into buf[cur^1]; land under compute below
        int kn = k0 + BKQ;
        if (kn < HID) {
            async16(Ag + (size_t)r0 * HID + kn + c0, &As[cur ^ 1][e0 * 8]);
            async16(Ag + (size_t)r1 * HID + kn + c1, &As[cur ^ 1][e1 * 8]);
            async16(Bg + (size_t)r0 * HID + kn + c0, &Bs[cur ^ 1][e0 * 8]);
            async16(Bg + (size_t)r1 * HID + kn + c1, &Bs[cur ^ 1][e1 * 8]);
        }

        bf16x8 af[4], bf[4];
#pragma unroll
        for (int t = 0; t < 4; t++)
            af[t] = *(const bf16x8*)&As[cur][(wm + t * 16 + l15) * BKQ + quad * 8];
#pragma unroll
        for (int t = 0; t < 4; t++)
            bf[t] = *(const bf16x8*)&Bs[cur][(wn + t * 16 + l15) * BKQ + quad * 8];
#pragma unroll
        for (int rt = 0; rt < 4; rt++)
#pragma unroll
            for (int ct = 0; ct < 4; ct++)
                acc[rt][ct] = __builtin_amdgcn_mfma_f32_16x16x32_bf16(
                    af[rt], bf[ct], acc[rt][ct], 0, 0, 0);

        // one barrier/iter: drains this wave's vmcnt(0) (next tile landed)
        // + all waves done reading buf[cur]
        __syncthreads();
        cur ^= 1;
    }

    // epilogue: C/D layout col = l15, row = quad*4 + r
#pragma unroll
    for (int ct = 0; ct < 4; ct++) {
        int n = n0 + wn + ct * 16 + l15;
        float bval = bias[n];
        int h = n >> 6, d = n & 63;
#pragma unroll
        for (int rt = 0; rt < 4; rt++) {
#pragma unroll
            for (int r = 0; r < 4; r++) {
                int m = m0 + wm + rt * 16 + quad * 4 + r;
                int b = m >> 11, s = m & (S_ - 1);
                float y = acc[rt][ct][r] + bval;
                size_t o = ((size_t)(b * H_ + h) * S_ + s) * D_ + d;
                if (z < 2) {
                    float c  = cosT[s * 64 + d];
                    float sn = sinT[s * 64 + d];
                    float p = __shfl_xor(y, 1);
                    float yr = ((d & 1) == 0) ? (y * c - p * sn) : (y * c + p * sn);
                    if (z == 0) { out[Q_OFF + o] = yr; Qb[o] = f2bf(yr); }
                    else        { out[K_OFF + o] = yr; Kb[o] = f2bf(yr); }
                } else {
                    Vb[o] = f2bf(y);
                }
            }
        }
    }
}

// ---------------------------------------------------------------------------
// Kernel 3b: transpose V: Vb[bh][s][d] -> Vt[bh][d][s]
// ---------------------------------------------------------------------------
__global__ __launch_bounds__(256) void transpose_v_kernel(
    const unsigned short* __restrict__ Vb, unsigned short* __restrict__ Vt)
{
    __shared__ unsigned short t[64][72];
    int bh = blockIdx.y;
    int s0 = blockIdx.x * 64;
    const unsigned short* src = Vb + ((size_t)bh * S_ + s0) * D_;
    unsigned short* dst = Vt + (size_t)bh * D_ * S_;
    int tid = threadIdx.x;
#pragma unroll
    for (int i = 0; i < 2; i++) {
        int e = i * 256 + tid;
        int row = e >> 3, c = (e & 7) * 8;
        u16x8 v = *(const u16x8*)(src + (size_t)row * D_ + c);
#pragma unroll
        for (int j = 0; j < 8; j++) t[row][c + j] = v[j];
    }
    __syncthreads();
#pragma unroll
    for (int i = 0; i < 2; i++) {
        int e = i * 256 + tid;
        int d = e >> 3, sc = (e & 7) * 8;
        u16x8 v;
#pragma unroll
        for (int j = 0; j < 8; j++) v[j] = t[sc + j][d];
        *(u16x8*)(dst + (size_t)d * S_ + s0 + sc) = v;
    }
}

// ---------------------------------------------------------------------------
// Kernel 4: flash attention (R12 verbatim — measured 124us).
// K/V double-buffered in padded LDS (TR=72), ONE barrier per kv-tile.
// P^T in registers via cvt_pk + permlane butterfly; exp via v_exp_f32.
// ---------------------------------------------------------------------------
#define TR 72          // padded tile row, u16

__global__ __launch_bounds__(256, 4) void attn_kernel(
    const unsigned short* __restrict__ Qb, const unsigned short* __restrict__ Kb,
    const unsigned short* __restrict__ Vt, const float* __restrict__ mask,
    float* __restrict__ out)
{
    __shared__ union {
        struct {
            unsigned short Ks[2][64 * TR];     // 18432 B
            unsigned short Vs[2][64 * TR];     // 18432 B
        } s;                                    // 36864 B
        float oT[4][2][16][68];                 // 34816 B (epilogue)
    } u;

    int h  = blockIdx.x;
    int qt = blockIdx.y;
    int b  = blockIdx.z;
    int tid = threadIdx.x;
    int wave = tid >> 6, lane = tid & 63;
    int quad = lane >> 4, l15 = lane & 15;

    size_t bh = (size_t)(b * H_ + h);
    const unsigned short* Qp = Qb + bh * S_ * D_;
    const unsigned short* Kp = Kb + bh * S_ * D_;
    const unsigned short* Vp = Vt + bh * D_ * S_;
    const float* mp = mask + (size_t)b * S_;

    // Q B-frags (n=q, k=d), held in registers for the whole loop
    bf16x8 qb[2][2];
#pragma unroll
    for (int qg = 0; qg < 2; qg++)
#pragma unroll
        for (int hf = 0; hf < 2; hf++) {
            int qrow = qt * 128 + qg * 64 + wave * 16 + l15;
            qb[qg][hf] = *(const bf16x8*)(Qp + (size_t)qrow * D_ + hf * 32 + quad * 8);
        }

    f32x4 o[2][4] = {};
    float psum[2] = {0.0f, 0.0f};
    const float C2    = 0.03125f * 1.44269504f;   // (1/sqrt(1024)) * log2(e)
    const float LOG2E = 1.44269504f;

    // staging granules: rows 0..31 (e=tid) and 32..63 (e=tid+256); same col
    int sr0 = tid >> 3, sg0 = (tid & 7) * 8;
    int sr1 = sr0 + 32;

    // prologue: load tile 0 into regs
    u16x8 kr0 = *(const u16x8*)(Kp + (size_t)sr0 * D_ + sg0);
    u16x8 kr1 = *(const u16x8*)(Kp + (size_t)sr1 * D_ + sg0);
    u16x8 vr0 = *(const u16x8*)(Vp + (size_t)sr0 * S_ + sg0);
    u16x8 vr1 = *(const u16x8*)(Vp + (size_t)sr1 * S_ + sg0);

    int cur = 0;
    for (int kv0 = 0; kv0 < S_; kv0 += 64) {
        // stage current tile into buf[cur] (vmcnt drain happens here)
        *(u16x8*)&u.s.Ks[cur][sr0 * TR + sg0] = kr0;
        *(u16x8*)&u.s.Ks[cur][sr1 * TR + sg0] = kr1;
        *(u16x8*)&u.s.Vs[cur][sr0 * TR + sg0] = vr0;
        *(u16x8*)&u.s.Vs[cur][sr1 * TR + sg0] = vr1;
        __syncthreads();

        // issue next tile's global loads (drain overlaps compute below)
        int kvn = (kv0 + 64 < S_) ? kv0 + 64 : 0;
        kr0 = *(const u16x8*)(Kp + (size_t)(kvn + sr0) * D_ + sg0);
        kr1 = *(const u16x8*)(Kp + (size_t)(kvn + sr1) * D_ + sg0);
        vr0 = *(const u16x8*)(Vp + (size_t)sr0 * S_ + kvn + sg0);
        vr1 = *(const u16x8*)(Vp + (size_t)sr1 * S_ + kvn + sg0);

        const unsigned short* Ksc = u.s.Ks[cur];
        const unsigned short* Vsc = u.s.Vs[cur];

        // S^T: A = K rows (m=kv), B = Q (n=q); K-frags shared across q-groups
        f32x4 sa[2][4] = {};
        __builtin_amdgcn_s_setprio(1);
#pragma unroll
        for (int mt = 0; mt < 4; mt++) {
            bf16x8 kf0 = *(const bf16x8*)&Ksc[(mt * 16 + l15) * TR + quad * 8];
            bf16x8 kf1 = *(const bf16x8*)&Ksc[(mt * 16 + l15) * TR + 32 + quad * 8];
#pragma unroll
            for (int qg = 0; qg < 2; qg++) {
                sa[qg][mt] = __builtin_amdgcn_mfma_f32_16x16x32_bf16(kf0, qb[qg][0], sa[qg][mt], 0, 0, 0);
                sa[qg][mt] = __builtin_amdgcn_mfma_f32_16x16x32_bf16(kf1, qb[qg][1], sa[qg][mt], 0, 0, 0);
            }
        }
        __builtin_amdgcn_s_setprio(0);

        // p = exp2(s*C2 + mask*log2e); pack pairs to bf16 in-register
        unsigned pw[2][4][2];
#pragma unroll
        for (int mt = 0; mt < 4; mt++) {
            f32x4 mkv = *(const f32x4*)(mp + kv0 + mt * 16 + quad * 4);
#pragma unroll
            for (int qg = 0; qg < 2; qg++) {
                f32x4 pv;
#pragma unroll
                for (int r = 0; r < 4; r++)
                    pv[r] = fast_exp2(sa[qg][mt][r] * C2 + mkv[r] * LOG2E);
                psum[qg] += (pv[0] + pv[1]) + (pv[2] + pv[3]);
                asm("v_cvt_pk_bf16_f32 %0, %1, %2"
                    : "=v"(pw[qg][mt][0]) : "v"(pv[0]), "v"(pv[1]));
                asm("v_cvt_pk_bf16_f32 %0, %1, %2"
                    : "=v"(pw[qg][mt][1]) : "v"(pv[2]), "v"(pv[3]));
            }
        }

        // quad butterfly: pw[qg][mt][t] (lane qs holds kv=mt*16+qs*4+2t,+1)
        // -> pb[qg][hf] word t' = P^T[q=l15][kv=hf*32+quad*8+2t',+1]
        bf16x8 pb[2][2];
#pragma unroll
        for (int qg = 0; qg < 2; qg++)
#pragma unroll
            for (int hf = 0; hf < 2; hf++) {
                union { unsigned w[4]; bf16x8 v; } pbu;
#pragma unroll
                for (int t = 0; t < 2; t++) {
                    unsigned A = pw[qg][2 * hf + 0][t];
                    unsigned B = pw[qg][2 * hf + 1][t];
                    u32x2 r1 = __builtin_amdgcn_permlane32_swap(A, B, false, false);
                    u32x2 r2 = __builtin_amdgcn_permlane16_swap(r1[0], r1[1], false, false);
                    pbu.w[t]     = r2[0];
                    pbu.w[2 + t] = r2[1];
                }
                pb[qg][hf] = pbu.v;
            }

        // PV: A = V^T rows (m=d), B = P^T in registers; V-frags shared
        __builtin_amdgcn_s_setprio(1);
#pragma unroll
        for (int ct = 0; ct < 4; ct++) {
            bf16x8 vf0 = *(const bf16x8*)&Vsc[(ct * 16 + l15) * TR + quad * 8];
            bf16x8 vf1 = *(const bf16x8*)&Vsc[(ct * 16 + l15) * TR + 32 + quad * 8];
#pragma unroll
            for (int qg = 0; qg < 2; qg++) {
                o[qg][ct] = __builtin_amdgcn_mfma_f32_16x16x32_bf16(vf0, pb[qg][0], o[qg][ct], 0, 0, 0);
                o[qg][ct] = __builtin_amdgcn_mfma_f32_16x16x32_bf16(vf1, pb[qg][1], o[qg][ct], 0, 0, 0);
            }
        }
        __builtin_amdgcn_s_setprio(0);

        cur ^= 1;
    }
    __syncthreads();   // protect union reuse (oT overlaps Ks/Vs)

    // l reduction over the 4 quads (kv partitions), once
#pragma unroll
    for (int qg = 0; qg < 2; qg++) {
        psum[qg] += __shfl_xor(psum[qg], 16);
        psum[qg] += __shfl_xor(psum[qg], 32);
    }

    // epilogue: normalize, transpose via LDS, coalesced store
#pragma unroll
    for (int qg = 0; qg < 2; qg++) {
        float inv = 1.0f / psum[qg];
#pragma unroll
        for (int ct = 0; ct < 4; ct++) {
            float4 vv;
            vv.x = o[qg][ct][0] * inv; vv.y = o[qg][ct][1] * inv;
            vv.z = o[qg][ct][2] * inv; vv.w = o[qg][ct][3] * inv;
            *(float4*)&u.oT[wave][qg][l15][ct * 16 + quad * 4] = vv;
        }
    }
    __builtin_amdgcn_wave_barrier();
    {
        int qq = lane >> 2, d0 = (lane & 3) * 16;
#pragma unroll
        for (int qg = 0; qg < 2; qg++) {
            int s_abs = qt * 128 + qg * 64 + wave * 16 + qq;
            float* dst = out + ((size_t)b * S_ + s_abs) * (H_ * D_) + h * D_ + d0;
#pragma unroll
            for (int j = 0; j < 4; j++) {
                float4 vj = *(float4*)&u.oT[wave][qg][qq][d0 + j * 4];
                *(float4*)(dst + j * 4) = vj;
            }
        }
    }
}

// ---------------------------------------------------------------------------
extern "C" void kernel_launch(void* const* d_in, const int* in_sizes, int n_in,
                              void* d_out, int out_size, void* d_ws, size_t ws_size,
                              hipStream_t stream)
{
    const float* X    = (const float*)d_in[0];
    const float* Wq   = (const float*)d_in[1];
    const float* bq   = (const float*)d_in[2];
    const float* Wk   = (const float*)d_in[3];
    const float* bk   = (const float*)d_in[4];
    const float* Wv   = (const float*)d_in[5];
    const float* bv   = (const float*)d_in[6];
    const float* mask = (const float*)d_in[7];

    char* ws = (char*)d_ws;
    unsigned short* Xb = (unsigned short*)(ws);                      // 16 MB (reused as Vt)
    unsigned short* Wt = (unsigned short*)(ws + 16777216);           //  6 MB
    unsigned short* Qb = (unsigned short*)(ws + 23068672);           // 16 MB
    unsigned short* Kb = (unsigned short*)(ws + 39845888);           // 16 MB
    unsigned short* Vb = (unsigned short*)(ws + 56623104);           // 16 MB
    unsigned short* Vt = Xb;   // Xb dead after qkv_gemm; reuse for V^T

    float* tab = (float*)d_out;   // RoPE tables in ctx region (overwritten by attn)

    rope_table_kernel<<<dim3(131072 / 256), 256, 0, stream>>>(tab);
    cast_x_kernel<<<dim3(M_ * HID / 4 / 256), 256, 0, stream>>>(X, Xb);
    cast_wt_kernel<<<dim3(16, 16, 3), 256, 0, stream>>>(Wq, Wk, Wv, Wt);
    qkv_gemm_kernel<<<dim3(HID / BN, M_ / BM, 3), 256, 0, stream>>>(
        Xb, Wt, bq, bk, bv, tab, tab + 131072, (float*)d_out, Qb, Kb, Vb);
    transpose_v_kernel<<<dim3(S_ / 64, B_ * H_), 256, 0, stream>>>(Vb, Vt);
    attn_kernel<<<dim3(H_, S_ / 128, B_), 256, 0, stream>>>(
        Qb, Kb, Vt, mask, (float*)d_out);
}

// Round 6
// 384.186 us; speedup vs baseline: 1.0212x; 1.0212x over previous
//
#include <hip/hip_runtime.h>

// ---------------------------------------------------------------------------
// MultiHeadsAttention: X[4,2048,1024] -> ctx[4,2048,1024], q[4,16,2048,64],
// k[4,16,2048,64] (q,k post-RoPE). fp32 in/out, bf16 MFMA internally.
// Round 14: R13 bundled two qkv changes; counters split them: XCD swizzle
// GOOD (FETCH 161->55.5MB = ideal), dbuf BAD (LDS 16->32KB + VGPR 76->96
// -> occupancy 27.8->18.5%, dur 124->159; re-confirms m99/m100 at lower
// occupancy). This round: keep swizzle, revert to R12's single-buffer
// 2-barrier loop. Staging loads are now ~250cy L2 hits (swizzle) instead
// of ~900cy HBM misses, and the restored occupancy hides them.
// attn frozen (R12-measured 124us).
// ---------------------------------------------------------------------------

#define B_  4
#define S_  2048
#define H_  16
#define D_  64
#define HID 1024
#define M_  (B_ * S_)          // 8192

typedef __attribute__((ext_vector_type(8))) short    bf16x8;
typedef __attribute__((ext_vector_type(4))) float    f32x4;
typedef __attribute__((ext_vector_type(4))) unsigned short u16x4;
typedef __attribute__((ext_vector_type(8))) unsigned short u16x8;
typedef __attribute__((ext_vector_type(2))) unsigned u32x2;

__device__ __forceinline__ unsigned short f2bf(float f) {
    union { float f; unsigned u; } v; v.f = f;
    unsigned r = v.u + 0x7fffu + ((v.u >> 16) & 1u);
    return (unsigned short)(r >> 16);
}

__device__ __forceinline__ void async16(const unsigned short* g, unsigned short* l) {
    __builtin_amdgcn_global_load_lds(
        (const __attribute__((address_space(1))) void*)g,
        (__attribute__((address_space(3))) void*)l, 16, 0, 0);
}

__device__ __forceinline__ float fast_exp2(float x) {
    float r;
    asm("v_exp_f32 %0, %1" : "=v"(r) : "v"(x));
    return r;
}

// ---------------------------------------------------------------------------
// Kernel 0: RoPE tables -> d_out ctx region (overwritten later by attn).
// ---------------------------------------------------------------------------
__global__ __launch_bounds__(256) void rope_table_kernel(float* __restrict__ tab)
{
    int i = blockIdx.x * 256 + threadIdx.x;     // 0 .. 131071
    int s = i >> 6, d = i & 63;
    const float NEG_LN1E4_32 = -0.28782313662425576f;  // -ln(10000)/32
    float freq = __expf(NEG_LN1E4_32 * (float)(d >> 1));
    float ang = (float)s * freq;
    tab[i]          = cosf(ang);
    tab[131072 + i] = sinf(ang);
}

// ---------------------------------------------------------------------------
// Kernel 1: cast X fp32 -> bf16
// ---------------------------------------------------------------------------
__global__ __launch_bounds__(256) void cast_x_kernel(
    const float* __restrict__ X, unsigned short* __restrict__ Xb)
{
    int i = (blockIdx.x * 256 + threadIdx.x) * 4;
    float4 v = *(const float4*)(X + i);
    u16x4 o;
    o[0] = f2bf(v.x); o[1] = f2bf(v.y); o[2] = f2bf(v.z); o[3] = f2bf(v.w);
    *(u16x4*)(Xb + i) = o;
}

// ---------------------------------------------------------------------------
// Kernel 2: transpose+cast W[k][n] fp32 -> Wt[n][k] bf16  (z selects q/k/v)
// ---------------------------------------------------------------------------
__global__ __launch_bounds__(256) void cast_wt_kernel(
    const float* __restrict__ Wq, const float* __restrict__ Wk,
    const float* __restrict__ Wv, unsigned short* __restrict__ Wt)
{
    __shared__ float tile[64][65];
    int z = blockIdx.z;
    const float* W = (z == 0) ? Wq : ((z == 1) ? Wk : Wv);
    unsigned short* out = Wt + (size_t)z * HID * HID;
    int n0 = blockIdx.x * 64, k0 = blockIdx.y * 64;
    int tx = threadIdx.x & 63, ty0 = threadIdx.x >> 6;
#pragma unroll
    for (int i = 0; i < 16; i++) {
        int ty = ty0 * 16 + i;
        tile[ty][tx] = W[(size_t)(k0 + ty) * HID + n0 + tx];
    }
    __syncthreads();
#pragma unroll
    for (int i = 0; i < 16; i++) {
        int ty = ty0 * 16 + i;
        out[(size_t)(n0 + ty) * HID + k0 + tx] = f2bf(tile[tx][ty]);
    }
}

// ---------------------------------------------------------------------------
// Kernel 3: QKV GEMM, 128x128 tile, BK=32, global_load_lds staging,
// 4 waves each 64x64 (4x4 frags of 16x16x32 MFMA). Bias + table-RoPE epilogue.
// Round 14: chunked XCD swizzle (kept from R13) + R12 single-buffer loop
// (dbuf reverted: it cost occupancy and 35us).
// ---------------------------------------------------------------------------
#define BM 128
#define BN 128
#define BKQ 32

__global__ __launch_bounds__(256) void qkv_gemm_kernel(
    const unsigned short* __restrict__ Xb, const unsigned short* __restrict__ Wt,
    const float* __restrict__ bq, const float* __restrict__ bk,
    const float* __restrict__ bv,
    const float* __restrict__ cosT, const float* __restrict__ sinT,
    float* out,
    unsigned short* __restrict__ Qb, unsigned short* __restrict__ Kb,
    unsigned short* __restrict__ Vb)
{
    __shared__ unsigned short As[BM * BKQ];   // row-major [128][32], unpadded
    __shared__ unsigned short Bs[BN * BKQ];   // (global_load_lds layout rule)

    const size_t Q_OFF = (size_t)B_ * S_ * HID;
    const size_t K_OFF = 2 * Q_OFF;

    // chunked XCD swizzle: lin = x + 8*(y + 64*z); 1536 blocks, 8 XCDs,
    // 192-block chunk per XCD, x-fastest within chunk -> the 8 n-blocks
    // sharing an A-tile run on ONE XCD (A-tile L2-reuse; B L2-resident).
    // R13 measured: FETCH 161MB -> 55.5MB (ideal).
    int lin = blockIdx.x + 8 * (blockIdx.y + 64 * blockIdx.z);
    int nl  = (lin & 7) * 192 + (lin >> 3);
    int z   = nl >> 9;
    int rem = nl & 511;
    int n0 = (rem & 7) * BN, m0 = (rem >> 3) * BM;

    const unsigned short* W = Wt + (size_t)z * HID * HID;
    const float* bias = (z == 0) ? bq : ((z == 1) ? bk : bv);

    int tid = threadIdx.x;
    int wave = tid >> 6, lane = tid & 63;
    int quad = lane >> 4, l15 = lane & 15;
    int wm = (wave >> 1) * 64;
    int wn = (wave & 1) * 64;

    const unsigned short* Ag = Xb + (size_t)m0 * HID;
    const unsigned short* Bg = W  + (size_t)n0 * HID;

    int e0 = tid, e1 = 256 + tid;
    int r0 = e0 >> 2, c0 = (e0 & 3) * 8;
    int r1 = e1 >> 2, c1 = (e1 & 3) * 8;

    f32x4 acc[4][4] = {};

    for (int k0 = 0; k0 < HID; k0 += BKQ) {
        async16(Ag + (size_t)r0 * HID + k0 + c0, &As[e0 * 8]);
        async16(Ag + (size_t)r1 * HID + k0 + c1, &As[e1 * 8]);
        async16(Bg + (size_t)r0 * HID + k0 + c0, &Bs[e0 * 8]);
        async16(Bg + (size_t)r1 * HID + k0 + c1, &Bs[e1 * 8]);
        __syncthreads();

        bf16x8 af[4], bf[4];
#pragma unroll
        for (int t = 0; t < 4; t++)
            af[t] = *(const bf16x8*)&As[(wm + t * 16 + l15) * BKQ + quad * 8];
#pragma unroll
        for (int t = 0; t < 4; t++)
            bf[t] = *(const bf16x8*)&Bs[(wn + t * 16 + l15) * BKQ + quad * 8];
#pragma unroll
        for (int rt = 0; rt < 4; rt++)
#pragma unroll
            for (int ct = 0; ct < 4; ct++)
                acc[rt][ct] = __builtin_amdgcn_mfma_f32_16x16x32_bf16(
                    af[rt], bf[ct], acc[rt][ct], 0, 0, 0);
        __syncthreads();
    }

    // epilogue: C/D layout col = l15, row = quad*4 + r
#pragma unroll
    for (int ct = 0; ct < 4; ct++) {
        int n = n0 + wn + ct * 16 + l15;
        float bval = bias[n];
        int h = n >> 6, d = n & 63;
#pragma unroll
        for (int rt = 0; rt < 4; rt++) {
#pragma unroll
            for (int r = 0; r < 4; r++) {
                int m = m0 + wm + rt * 16 + quad * 4 + r;
                int b = m >> 11, s = m & (S_ - 1);
                float y = acc[rt][ct][r] + bval;
                size_t o = ((size_t)(b * H_ + h) * S_ + s) * D_ + d;
                if (z < 2) {
                    float c  = cosT[s * 64 + d];
                    float sn = sinT[s * 64 + d];
                    float p = __shfl_xor(y, 1);
                    float yr = ((d & 1) == 0) ? (y * c - p * sn) : (y * c + p * sn);
                    if (z == 0) { out[Q_OFF + o] = yr; Qb[o] = f2bf(yr); }
                    else        { out[K_OFF + o] = yr; Kb[o] = f2bf(yr); }
                } else {
                    Vb[o] = f2bf(y);
                }
            }
        }
    }
}

// ---------------------------------------------------------------------------
// Kernel 3b: transpose V: Vb[bh][s][d] -> Vt[bh][d][s]
// ---------------------------------------------------------------------------
__global__ __launch_bounds__(256) void transpose_v_kernel(
    const unsigned short* __restrict__ Vb, unsigned short* __restrict__ Vt)
{
    __shared__ unsigned short t[64][72];
    int bh = blockIdx.y;
    int s0 = blockIdx.x * 64;
    const unsigned short* src = Vb + ((size_t)bh * S_ + s0) * D_;
    unsigned short* dst = Vt + (size_t)bh * D_ * S_;
    int tid = threadIdx.x;
#pragma unroll
    for (int i = 0; i < 2; i++) {
        int e = i * 256 + tid;
        int row = e >> 3, c = (e & 7) * 8;
        u16x8 v = *(const u16x8*)(src + (size_t)row * D_ + c);
#pragma unroll
        for (int j = 0; j < 8; j++) t[row][c + j] = v[j];
    }
    __syncthreads();
#pragma unroll
    for (int i = 0; i < 2; i++) {
        int e = i * 256 + tid;
        int d = e >> 3, sc = (e & 7) * 8;
        u16x8 v;
#pragma unroll
        for (int j = 0; j < 8; j++) v[j] = t[sc + j][d];
        *(u16x8*)(dst + (size_t)d * S_ + s0 + sc) = v;
    }
}

// ---------------------------------------------------------------------------
// Kernel 4: flash attention (R12 verbatim — measured 124us).
// K/V double-buffered in padded LDS (TR=72), ONE barrier per kv-tile.
// P^T in registers via cvt_pk + permlane butterfly; exp via v_exp_f32.
// ---------------------------------------------------------------------------
#define TR 72          // padded tile row, u16

__global__ __launch_bounds__(256, 4) void attn_kernel(
    const unsigned short* __restrict__ Qb, const unsigned short* __restrict__ Kb,
    const unsigned short* __restrict__ Vt, const float* __restrict__ mask,
    float* __restrict__ out)
{
    __shared__ union {
        struct {
            unsigned short Ks[2][64 * TR];     // 18432 B
            unsigned short Vs[2][64 * TR];     // 18432 B
        } s;                                    // 36864 B
        float oT[4][2][16][68];                 // 34816 B (epilogue)
    } u;

    int h  = blockIdx.x;
    int qt = blockIdx.y;
    int b  = blockIdx.z;
    int tid = threadIdx.x;
    int wave = tid >> 6, lane = tid & 63;
    int quad = lane >> 4, l15 = lane & 15;

    size_t bh = (size_t)(b * H_ + h);
    const unsigned short* Qp = Qb + bh * S_ * D_;
    const unsigned short* Kp = Kb + bh * S_ * D_;
    const unsigned short* Vp = Vt + bh * D_ * S_;
    const float* mp = mask + (size_t)b * S_;

    // Q B-frags (n=q, k=d), held in registers for the whole loop
    bf16x8 qb[2][2];
#pragma unroll
    for (int qg = 0; qg < 2; qg++)
#pragma unroll
        for (int hf = 0; hf < 2; hf++) {
            int qrow = qt * 128 + qg * 64 + wave * 16 + l15;
            qb[qg][hf] = *(const bf16x8*)(Qp + (size_t)qrow * D_ + hf * 32 + quad * 8);
        }

    f32x4 o[2][4] = {};
    float psum[2] = {0.0f, 0.0f};
    const float C2    = 0.03125f * 1.44269504f;   // (1/sqrt(1024)) * log2(e)
    const float LOG2E = 1.44269504f;

    // staging granules: rows 0..31 (e=tid) and 32..63 (e=tid+256); same col
    int sr0 = tid >> 3, sg0 = (tid & 7) * 8;
    int sr1 = sr0 + 32;

    // prologue: load tile 0 into regs
    u16x8 kr0 = *(const u16x8*)(Kp + (size_t)sr0 * D_ + sg0);
    u16x8 kr1 = *(const u16x8*)(Kp + (size_t)sr1 * D_ + sg0);
    u16x8 vr0 = *(const u16x8*)(Vp + (size_t)sr0 * S_ + sg0);
    u16x8 vr1 = *(const u16x8*)(Vp + (size_t)sr1 * S_ + sg0);

    int cur = 0;
    for (int kv0 = 0; kv0 < S_; kv0 += 64) {
        // stage current tile into buf[cur] (vmcnt drain happens here)
        *(u16x8*)&u.s.Ks[cur][sr0 * TR + sg0] = kr0;
        *(u16x8*)&u.s.Ks[cur][sr1 * TR + sg0] = kr1;
        *(u16x8*)&u.s.Vs[cur][sr0 * TR + sg0] = vr0;
        *(u16x8*)&u.s.Vs[cur][sr1 * TR + sg0] = vr1;
        __syncthreads();

        // issue next tile's global loads (drain overlaps compute below)
        int kvn = (kv0 + 64 < S_) ? kv0 + 64 : 0;
        kr0 = *(const u16x8*)(Kp + (size_t)(kvn + sr0) * D_ + sg0);
        kr1 = *(const u16x8*)(Kp + (size_t)(kvn + sr1) * D_ + sg0);
        vr0 = *(const u16x8*)(Vp + (size_t)sr0 * S_ + kvn + sg0);
        vr1 = *(const u16x8*)(Vp + (size_t)sr1 * S_ + kvn + sg0);

        const unsigned short* Ksc = u.s.Ks[cur];
        const unsigned short* Vsc = u.s.Vs[cur];

        // S^T: A = K rows (m=kv), B = Q (n=q); K-frags shared across q-groups
        f32x4 sa[2][4] = {};
        __builtin_amdgcn_s_setprio(1);
#pragma unroll
        for (int mt = 0; mt < 4; mt++) {
            bf16x8 kf0 = *(const bf16x8*)&Ksc[(mt * 16 + l15) * TR + quad * 8];
            bf16x8 kf1 = *(const bf16x8*)&Ksc[(mt * 16 + l15) * TR + 32 + quad * 8];
#pragma unroll
            for (int qg = 0; qg < 2; qg++) {
                sa[qg][mt] = __builtin_amdgcn_mfma_f32_16x16x32_bf16(kf0, qb[qg][0], sa[qg][mt], 0, 0, 0);
                sa[qg][mt] = __builtin_amdgcn_mfma_f32_16x16x32_bf16(kf1, qb[qg][1], sa[qg][mt], 0, 0, 0);
            }
        }
        __builtin_amdgcn_s_setprio(0);

        // p = exp2(s*C2 + mask*log2e); pack pairs to bf16 in-register
        unsigned pw[2][4][2];
#pragma unroll
        for (int mt = 0; mt < 4; mt++) {
            f32x4 mkv = *(const f32x4*)(mp + kv0 + mt * 16 + quad * 4);
#pragma unroll
            for (int qg = 0; qg < 2; qg++) {
                f32x4 pv;
#pragma unroll
                for (int r = 0; r < 4; r++)
                    pv[r] = fast_exp2(sa[qg][mt][r] * C2 + mkv[r] * LOG2E);
                psum[qg] += (pv[0] + pv[1]) + (pv[2] + pv[3]);
                asm("v_cvt_pk_bf16_f32 %0, %1, %2"
                    : "=v"(pw[qg][mt][0]) : "v"(pv[0]), "v"(pv[1]));
                asm("v_cvt_pk_bf16_f32 %0, %1, %2"
                    : "=v"(pw[qg][mt][1]) : "v"(pv[2]), "v"(pv[3]));
            }
        }

        // quad butterfly: pw[qg][mt][t] (lane qs holds kv=mt*16+qs*4+2t,+1)
        // -> pb[qg][hf] word t' = P^T[q=l15][kv=hf*32+quad*8+2t',+1]
        bf16x8 pb[2][2];
#pragma unroll
        for (int qg = 0; qg < 2; qg++)
#pragma unroll
            for (int hf = 0; hf < 2; hf++) {
                union { unsigned w[4]; bf16x8 v; } pbu;
#pragma unroll
                for (int t = 0; t < 2; t++) {
                    unsigned A = pw[qg][2 * hf + 0][t];
                    unsigned B = pw[qg][2 * hf + 1][t];
                    u32x2 r1 = __builtin_amdgcn_permlane32_swap(A, B, false, false);
                    u32x2 r2 = __builtin_amdgcn_permlane16_swap(r1[0], r1[1], false, false);
                    pbu.w[t]     = r2[0];
                    pbu.w[2 + t] = r2[1];
                }
                pb[qg][hf] = pbu.v;
            }

        // PV: A = V^T rows (m=d), B = P^T in registers; V-frags shared
        __builtin_amdgcn_s_setprio(1);
#pragma unroll
        for (int ct = 0; ct < 4; ct++) {
            bf16x8 vf0 = *(const bf16x8*)&Vsc[(ct * 16 + l15) * TR + quad * 8];
            bf16x8 vf1 = *(const bf16x8*)&Vsc[(ct * 16 + l15) * TR + 32 + quad * 8];
#pragma unroll
            for (int qg = 0; qg < 2; qg++) {
                o[qg][ct] = __builtin_amdgcn_mfma_f32_16x16x32_bf16(vf0, pb[qg][0], o[qg][ct], 0, 0, 0);
                o[qg][ct] = __builtin_amdgcn_mfma_f32_16x16x32_bf16(vf1, pb[qg][1], o[qg][ct], 0, 0, 0);
            }
        }
        __builtin_amdgcn_s_setprio(0);

        cur ^= 1;
    }
    __syncthreads();   // protect union reuse (oT overlaps Ks/Vs)

    // l reduction over the 4 quads (kv partitions), once
#pragma unroll
    for (int qg = 0; qg < 2; qg++) {
        psum[qg] += __shfl_xor(psum[qg], 16);
        psum[qg] += __shfl_xor(psum[qg], 32);
    }

    // epilogue: normalize, transpose via LDS, coalesced store
#pragma unroll
    for (int qg = 0; qg < 2; qg++) {
        float inv = 1.0f / psum[qg];
#pragma unroll
        for (int ct = 0; ct < 4; ct++) {
            float4 vv;
            vv.x = o[qg][ct][0] * inv; vv.y = o[qg][ct][1] * inv;
            vv.z = o[qg][ct][2] * inv; vv.w = o[qg][ct][3] * inv;
            *(float4*)&u.oT[wave][qg][l15][ct * 16 + quad * 4] = vv;
        }
    }
    __builtin_amdgcn_wave_barrier();
    {
        int qq = lane >> 2, d0 = (lane & 3) * 16;
#pragma unroll
        for (int qg = 0; qg < 2; qg++) {
            int s_abs = qt * 128 + qg * 64 + wave * 16 + qq;
            float* dst = out + ((size_t)b * S_ + s_abs) * (H_ * D_) + h * D_ + d0;
#pragma unroll
            for (int j = 0; j < 4; j++) {
                float4 vj = *(float4*)&u.oT[wave][qg][qq][d0 + j * 4];
                *(float4*)(dst + j * 4) = vj;
            }
        }
    }
}

// ---------------------------------------------------------------------------
extern "C" void kernel_launch(void* const* d_in, const int* in_sizes, int n_in,
                              void* d_out, int out_size, void* d_ws, size_t ws_size,
                              hipStream_t stream)
{
    const float* X    = (const float*)d_in[0];
    const float* Wq   = (const float*)d_in[1];
    const float* bq   = (const float*)d_in[2];
    const float* Wk   = (const float*)d_in[3];
    const float* bk   = (const float*)d_in[4];
    const float* Wv   = (const float*)d_in[5];
    const float* bv   = (const float*)d_in[6];
    const float* mask = (const float*)d_in[7];

    char* ws = (char*)d_ws;
    unsigned short* Xb = (unsigned short*)(ws);                      // 16 MB (reused as Vt)
    unsigned short* Wt = (unsigned short*)(ws + 16777216);           //  6 MB
    unsigned short* Qb = (unsigned short*)(ws + 23068672);           // 16 MB
    unsigned short* Kb = (unsigned short*)(ws + 39845888);           // 16 MB
    unsigned short* Vb = (unsigned short*)(ws + 56623104);           // 16 MB
    unsigned short* Vt = Xb;   // Xb dead after qkv_gemm; reuse for V^T

    float* tab = (float*)d_out;   // RoPE tables in ctx region (overwritten by attn)

    rope_table_kernel<<<dim3(131072 / 256), 256, 0, stream>>>(tab);
    cast_x_kernel<<<dim3(M_ * HID / 4 / 256), 256, 0, stream>>>(X, Xb);
    cast_wt_kernel<<<dim3(16, 16, 3), 256, 0, stream>>>(Wq, Wk, Wv, Wt);
    qkv_gemm_kernel<<<dim3(HID / BN, M_ / BM, 3), 256, 0, stream>>>(
        Xb, Wt, bq, bk, bv, tab, tab + 131072, (float*)d_out, Qb, Kb, Vb);
    transpose_v_kernel<<<dim3(S_ / 64, B_ * H_), 256, 0, stream>>>(Vb, Vt);
    attn_kernel<<<dim3(H_, S_ / 128, B_), 256, 0, stream>>>(
        Qb, Kb, Vt, mask, (float*)d_out);
}

// Round 7
// 371.890 us; speedup vs baseline: 1.0550x; 1.0331x over previous
//
#include <hip/hip_runtime.h>

// ---------------------------------------------------------------------------
// MultiHeadsAttention: X[4,2048,1024] -> ctx[4,2048,1024], q[4,16,2048,64],
// k[4,16,2048,64] (q,k post-RoPE). fp32 in/out, bf16 MFMA internally.
// Round 15: R14 A/B concluded the XCD swizzle is net-negative (-35us)
// despite ideal FETCH (53MB): HBM was never the constraint, and same-XCD
// lockstep A-reads pile onto the same pending L2 lines (MSHR wait ~= HBM
// latency for all siblings). REVERTED. This round attacks the real stall:
// __syncthreads() drains vmcnt(0) right after the global_load_lds issue
// (m97 ceiling mechanism, ~900cy exposed/iter). qkv now uses the T3/T4
// counted-vmcnt pipeline: double-buffered LDS, raw s_barrier, vmcnt(4) —
// tile i+1's loads stay in flight across the barrier; tile i's loads were
// issued a FULL iteration earlier. attn + prep kernels frozen.
// ---------------------------------------------------------------------------

#define B_  4
#define S_  2048
#define H_  16
#define D_  64
#define HID 1024
#define M_  (B_ * S_)          // 8192

typedef __attribute__((ext_vector_type(8))) short    bf16x8;
typedef __attribute__((ext_vector_type(4))) float    f32x4;
typedef __attribute__((ext_vector_type(4))) unsigned short u16x4;
typedef __attribute__((ext_vector_type(8))) unsigned short u16x8;
typedef __attribute__((ext_vector_type(2))) unsigned u32x2;

__device__ __forceinline__ unsigned short f2bf(float f) {
    union { float f; unsigned u; } v; v.f = f;
    unsigned r = v.u + 0x7fffu + ((v.u >> 16) & 1u);
    return (unsigned short)(r >> 16);
}

__device__ __forceinline__ void async16(const unsigned short* g, unsigned short* l) {
    __builtin_amdgcn_global_load_lds(
        (const __attribute__((address_space(1))) void*)g,
        (__attribute__((address_space(3))) void*)l, 16, 0, 0);
}

__device__ __forceinline__ float fast_exp2(float x) {
    float r;
    asm("v_exp_f32 %0, %1" : "=v"(r) : "v"(x));
    return r;
}

// ---------------------------------------------------------------------------
// Kernel 0: RoPE tables -> d_out ctx region (overwritten later by attn).
// ---------------------------------------------------------------------------
__global__ __launch_bounds__(256) void rope_table_kernel(float* __restrict__ tab)
{
    int i = blockIdx.x * 256 + threadIdx.x;     // 0 .. 131071
    int s = i >> 6, d = i & 63;
    const float NEG_LN1E4_32 = -0.28782313662425576f;  // -ln(10000)/32
    float freq = __expf(NEG_LN1E4_32 * (float)(d >> 1));
    float ang = (float)s * freq;
    tab[i]          = cosf(ang);
    tab[131072 + i] = sinf(ang);
}

// ---------------------------------------------------------------------------
// Kernel 1: cast X fp32 -> bf16
// ---------------------------------------------------------------------------
__global__ __launch_bounds__(256) void cast_x_kernel(
    const float* __restrict__ X, unsigned short* __restrict__ Xb)
{
    int i = (blockIdx.x * 256 + threadIdx.x) * 4;
    float4 v = *(const float4*)(X + i);
    u16x4 o;
    o[0] = f2bf(v.x); o[1] = f2bf(v.y); o[2] = f2bf(v.z); o[3] = f2bf(v.w);
    *(u16x4*)(Xb + i) = o;
}

// ---------------------------------------------------------------------------
// Kernel 2: transpose+cast W[k][n] fp32 -> Wt[n][k] bf16  (z selects q/k/v)
// ---------------------------------------------------------------------------
__global__ __launch_bounds__(256) void cast_wt_kernel(
    const float* __restrict__ Wq, const float* __restrict__ Wk,
    const float* __restrict__ Wv, unsigned short* __restrict__ Wt)
{
    __shared__ float tile[64][65];
    int z = blockIdx.z;
    const float* W = (z == 0) ? Wq : ((z == 1) ? Wk : Wv);
    unsigned short* out = Wt + (size_t)z * HID * HID;
    int n0 = blockIdx.x * 64, k0 = blockIdx.y * 64;
    int tx = threadIdx.x & 63, ty0 = threadIdx.x >> 6;
#pragma unroll
    for (int i = 0; i < 16; i++) {
        int ty = ty0 * 16 + i;
        tile[ty][tx] = W[(size_t)(k0 + ty) * HID + n0 + tx];
    }
    __syncthreads();
#pragma unroll
    for (int i = 0; i < 16; i++) {
        int ty = ty0 * 16 + i;
        out[(size_t)(n0 + ty) * HID + k0 + tx] = f2bf(tile[tx][ty]);
    }
}

// ---------------------------------------------------------------------------
// Kernel 3: QKV GEMM, 128x128 tile, BK=32, global_load_lds staging,
// 4 waves each 64x64 (4x4 frags of 16x16x32 MFMA). Bias + table-RoPE epilogue.
// Round 15: T3/T4 pipeline — LDS dbuf (2x16KB), raw s_barrier, counted
// vmcnt(4): tile i+1's loads cross the barrier in flight; the wait is for
// tile i's loads issued one full iteration (~600cy+) earlier.
// ---------------------------------------------------------------------------
#define BM 128
#define BN 128
#define BKQ 32

__global__ __launch_bounds__(256) void qkv_gemm_kernel(
    const unsigned short* __restrict__ Xb, const unsigned short* __restrict__ Wt,
    const float* __restrict__ bq, const float* __restrict__ bk,
    const float* __restrict__ bv,
    const float* __restrict__ cosT, const float* __restrict__ sinT,
    float* out,
    unsigned short* __restrict__ Qb, unsigned short* __restrict__ Kb,
    unsigned short* __restrict__ Vb)
{
    __shared__ unsigned short As[2][BM * BKQ];   // 2 x 8 KB
    __shared__ unsigned short Bs[2][BN * BKQ];   // 2 x 8 KB

    const size_t Q_OFF = (size_t)B_ * S_ * HID;
    const size_t K_OFF = 2 * Q_OFF;

    int z = blockIdx.z;
    const unsigned short* W = Wt + (size_t)z * HID * HID;
    const float* bias = (z == 0) ? bq : ((z == 1) ? bk : bv);

    int n0 = blockIdx.x * BN, m0 = blockIdx.y * BM;
    int tid = threadIdx.x;
    int wave = tid >> 6, lane = tid & 63;
    int quad = lane >> 4, l15 = lane & 15;
    int wm = (wave >> 1) * 64;
    int wn = (wave & 1) * 64;

    const unsigned short* Ag = Xb + (size_t)m0 * HID;
    const unsigned short* Bg = W  + (size_t)n0 * HID;

    int e0 = tid, e1 = 256 + tid;
    int r0 = e0 >> 2, c0 = (e0 & 3) * 8;
    int r1 = e1 >> 2, c1 = (e1 & 3) * 8;

    f32x4 acc[4][4] = {};

    // prologue: issue tile 0 loads into buf 0 (4 per thread, stay in flight)
    async16(Ag + (size_t)r0 * HID + c0, &As[0][e0 * 8]);
    async16(Ag + (size_t)r1 * HID + c1, &As[0][e1 * 8]);
    async16(Bg + (size_t)r0 * HID + c0, &Bs[0][e0 * 8]);
    async16(Bg + (size_t)r1 * HID + c1, &Bs[0][e1 * 8]);

    int cur = 0;
    for (int k0 = 0; k0 < HID; k0 += BKQ) {
        // issue tile i+1 loads into buf[cur^1]; last iter wraps to k=0
        // (harmless dummy prefetch, keeps vmcnt accounting uniform).
        int kn = (k0 + BKQ < HID) ? k0 + BKQ : 0;
        async16(Ag + (size_t)r0 * HID + kn + c0, &As[cur ^ 1][e0 * 8]);
        async16(Ag + (size_t)r1 * HID + kn + c1, &As[cur ^ 1][e1 * 8]);
        async16(Bg + (size_t)r0 * HID + kn + c0, &Bs[cur ^ 1][e0 * 8]);
        async16(Bg + (size_t)r1 * HID + kn + c1, &Bs[cur ^ 1][e1 * 8]);

        // wait only for tile i's 4 loads (issued one iteration ago);
        // the 4 just-issued stay in flight across the barrier (T4).
        __builtin_amdgcn_sched_barrier(0);
        asm volatile("s_waitcnt vmcnt(4)" ::: "memory");
        __builtin_amdgcn_s_barrier();          // A: tile i visible to all waves
        __builtin_amdgcn_sched_barrier(0);

        bf16x8 af[4], bf[4];
#pragma unroll
        for (int t = 0; t < 4; t++)
            af[t] = *(const bf16x8*)&As[cur][(wm + t * 16 + l15) * BKQ + quad * 8];
#pragma unroll
        for (int t = 0; t < 4; t++)
            bf[t] = *(const bf16x8*)&Bs[cur][(wn + t * 16 + l15) * BKQ + quad * 8];
#pragma unroll
        for (int rt = 0; rt < 4; rt++)
#pragma unroll
            for (int ct = 0; ct < 4; ct++)
                acc[rt][ct] = __builtin_amdgcn_mfma_f32_16x16x32_bf16(
                    af[rt], bf[ct], acc[rt][ct], 0, 0, 0);

        // B: all waves' ds_reads of buf[cur] complete (lgkm is in-order and
        // the MFMAs waited on them) -> next iter may overwrite buf[cur].
        __builtin_amdgcn_sched_barrier(0);
        __builtin_amdgcn_s_barrier();
        __builtin_amdgcn_sched_barrier(0);
        cur ^= 1;
    }

    // epilogue: C/D layout col = l15, row = quad*4 + r
#pragma unroll
    for (int ct = 0; ct < 4; ct++) {
        int n = n0 + wn + ct * 16 + l15;
        float bval = bias[n];
        int h = n >> 6, d = n & 63;
#pragma unroll
        for (int rt = 0; rt < 4; rt++) {
#pragma unroll
            for (int r = 0; r < 4; r++) {
                int m = m0 + wm + rt * 16 + quad * 4 + r;
                int b = m >> 11, s = m & (S_ - 1);
                float y = acc[rt][ct][r] + bval;
                size_t o = ((size_t)(b * H_ + h) * S_ + s) * D_ + d;
                if (z < 2) {
                    float c  = cosT[s * 64 + d];
                    float sn = sinT[s * 64 + d];
                    float p = __shfl_xor(y, 1);
                    float yr = ((d & 1) == 0) ? (y * c - p * sn) : (y * c + p * sn);
                    if (z == 0) { out[Q_OFF + o] = yr; Qb[o] = f2bf(yr); }
                    else        { out[K_OFF + o] = yr; Kb[o] = f2bf(yr); }
                } else {
                    Vb[o] = f2bf(y);
                }
            }
        }
    }
}

// ---------------------------------------------------------------------------
// Kernel 3b: transpose V: Vb[bh][s][d] -> Vt[bh][d][s]
// ---------------------------------------------------------------------------
__global__ __launch_bounds__(256) void transpose_v_kernel(
    const unsigned short* __restrict__ Vb, unsigned short* __restrict__ Vt)
{
    __shared__ unsigned short t[64][72];
    int bh = blockIdx.y;
    int s0 = blockIdx.x * 64;
    const unsigned short* src = Vb + ((size_t)bh * S_ + s0) * D_;
    unsigned short* dst = Vt + (size_t)bh * D_ * S_;
    int tid = threadIdx.x;
#pragma unroll
    for (int i = 0; i < 2; i++) {
        int e = i * 256 + tid;
        int row = e >> 3, c = (e & 7) * 8;
        u16x8 v = *(const u16x8*)(src + (size_t)row * D_ + c);
#pragma unroll
        for (int j = 0; j < 8; j++) t[row][c + j] = v[j];
    }
    __syncthreads();
#pragma unroll
    for (int i = 0; i < 2; i++) {
        int e = i * 256 + tid;
        int d = e >> 3, sc = (e & 7) * 8;
        u16x8 v;
#pragma unroll
        for (int j = 0; j < 8; j++) v[j] = t[sc + j][d];
        *(u16x8*)(dst + (size_t)d * S_ + s0 + sc) = v;
    }
}

// ---------------------------------------------------------------------------
// Kernel 4: flash attention (R12 verbatim — measured 124us).
// K/V double-buffered in padded LDS (TR=72), ONE barrier per kv-tile.
// P^T in registers via cvt_pk + permlane butterfly; exp via v_exp_f32.
// ---------------------------------------------------------------------------
#define TR 72          // padded tile row, u16

__global__ __launch_bounds__(256, 4) void attn_kernel(
    const unsigned short* __restrict__ Qb, const unsigned short* __restrict__ Kb,
    const unsigned short* __restrict__ Vt, const float* __restrict__ mask,
    float* __restrict__ out)
{
    __shared__ union {
        struct {
            unsigned short Ks[2][64 * TR];     // 18432 B
            unsigned short Vs[2][64 * TR];     // 18432 B
        } s;                                    // 36864 B
        float oT[4][2][16][68];                 // 34816 B (epilogue)
    } u;

    int h  = blockIdx.x;
    int qt = blockIdx.y;
    int b  = blockIdx.z;
    int tid = threadIdx.x;
    int wave = tid >> 6, lane = tid & 63;
    int quad = lane >> 4, l15 = lane & 15;

    size_t bh = (size_t)(b * H_ + h);
    const unsigned short* Qp = Qb + bh * S_ * D_;
    const unsigned short* Kp = Kb + bh * S_ * D_;
    const unsigned short* Vp = Vt + bh * D_ * S_;
    const float* mp = mask + (size_t)b * S_;

    // Q B-frags (n=q, k=d), held in registers for the whole loop
    bf16x8 qb[2][2];
#pragma unroll
    for (int qg = 0; qg < 2; qg++)
#pragma unroll
        for (int hf = 0; hf < 2; hf++) {
            int qrow = qt * 128 + qg * 64 + wave * 16 + l15;
            qb[qg][hf] = *(const bf16x8*)(Qp + (size_t)qrow * D_ + hf * 32 + quad * 8);
        }

    f32x4 o[2][4] = {};
    float psum[2] = {0.0f, 0.0f};
    const float C2    = 0.03125f * 1.44269504f;   // (1/sqrt(1024)) * log2(e)
    const float LOG2E = 1.44269504f;

    // staging granules: rows 0..31 (e=tid) and 32..63 (e=tid+256); same col
    int sr0 = tid >> 3, sg0 = (tid & 7) * 8;
    int sr1 = sr0 + 32;

    // prologue: load tile 0 into regs
    u16x8 kr0 = *(const u16x8*)(Kp + (size_t)sr0 * D_ + sg0);
    u16x8 kr1 = *(const u16x8*)(Kp + (size_t)sr1 * D_ + sg0);
    u16x8 vr0 = *(const u16x8*)(Vp + (size_t)sr0 * S_ + sg0);
    u16x8 vr1 = *(const u16x8*)(Vp + (size_t)sr1 * S_ + sg0);

    int cur = 0;
    for (int kv0 = 0; kv0 < S_; kv0 += 64) {
        // stage current tile into buf[cur] (vmcnt drain happens here)
        *(u16x8*)&u.s.Ks[cur][sr0 * TR + sg0] = kr0;
        *(u16x8*)&u.s.Ks[cur][sr1 * TR + sg0] = kr1;
        *(u16x8*)&u.s.Vs[cur][sr0 * TR + sg0] = vr0;
        *(u16x8*)&u.s.Vs[cur][sr1 * TR + sg0] = vr1;
        __syncthreads();

        // issue next tile's global loads (drain overlaps compute below)
        int kvn = (kv0 + 64 < S_) ? kv0 + 64 : 0;
        kr0 = *(const u16x8*)(Kp + (size_t)(kvn + sr0) * D_ + sg0);
        kr1 = *(const u16x8*)(Kp + (size_t)(kvn + sr1) * D_ + sg0);
        vr0 = *(const u16x8*)(Vp + (size_t)sr0 * S_ + kvn + sg0);
        vr1 = *(const u16x8*)(Vp + (size_t)sr1 * S_ + kvn + sg0);

        const unsigned short* Ksc = u.s.Ks[cur];
        const unsigned short* Vsc = u.s.Vs[cur];

        // S^T: A = K rows (m=kv), B = Q (n=q); K-frags shared across q-groups
        f32x4 sa[2][4] = {};
        __builtin_amdgcn_s_setprio(1);
#pragma unroll
        for (int mt = 0; mt < 4; mt++) {
            bf16x8 kf0 = *(const bf16x8*)&Ksc[(mt * 16 + l15) * TR + quad * 8];
            bf16x8 kf1 = *(const bf16x8*)&Ksc[(mt * 16 + l15) * TR + 32 + quad * 8];
#pragma unroll
            for (int qg = 0; qg < 2; qg++) {
                sa[qg][mt] = __builtin_amdgcn_mfma_f32_16x16x32_bf16(kf0, qb[qg][0], sa[qg][mt], 0, 0, 0);
                sa[qg][mt] = __builtin_amdgcn_mfma_f32_16x16x32_bf16(kf1, qb[qg][1], sa[qg][mt], 0, 0, 0);
            }
        }
        __builtin_amdgcn_s_setprio(0);

        // p = exp2(s*C2 + mask*log2e); pack pairs to bf16 in-register
        unsigned pw[2][4][2];
#pragma unroll
        for (int mt = 0; mt < 4; mt++) {
            f32x4 mkv = *(const f32x4*)(mp + kv0 + mt * 16 + quad * 4);
#pragma unroll
            for (int qg = 0; qg < 2; qg++) {
                f32x4 pv;
#pragma unroll
                for (int r = 0; r < 4; r++)
                    pv[r] = fast_exp2(sa[qg][mt][r] * C2 + mkv[r] * LOG2E);
                psum[qg] += (pv[0] + pv[1]) + (pv[2] + pv[3]);
                asm("v_cvt_pk_bf16_f32 %0, %1, %2"
                    : "=v"(pw[qg][mt][0]) : "v"(pv[0]), "v"(pv[1]));
                asm("v_cvt_pk_bf16_f32 %0, %1, %2"
                    : "=v"(pw[qg][mt][1]) : "v"(pv[2]), "v"(pv[3]));
            }
        }

        // quad butterfly: pw[qg][mt][t] (lane qs holds kv=mt*16+qs*4+2t,+1)
        // -> pb[qg][hf] word t' = P^T[q=l15][kv=hf*32+quad*8+2t',+1]
        bf16x8 pb[2][2];
#pragma unroll
        for (int qg = 0; qg < 2; qg++)
#pragma unroll
            for (int hf = 0; hf < 2; hf++) {
                union { unsigned w[4]; bf16x8 v; } pbu;
#pragma unroll
                for (int t = 0; t < 2; t++) {
                    unsigned A = pw[qg][2 * hf + 0][t];
                    unsigned B = pw[qg][2 * hf + 1][t];
                    u32x2 r1 = __builtin_amdgcn_permlane32_swap(A, B, false, false);
                    u32x2 r2 = __builtin_amdgcn_permlane16_swap(r1[0], r1[1], false, false);
                    pbu.w[t]     = r2[0];
                    pbu.w[2 + t] = r2[1];
                }
                pb[qg][hf] = pbu.v;
            }

        // PV: A = V^T rows (m=d), B = P^T in registers; V-frags shared
        __builtin_amdgcn_s_setprio(1);
#pragma unroll
        for (int ct = 0; ct < 4; ct++) {
            bf16x8 vf0 = *(const bf16x8*)&Vsc[(ct * 16 + l15) * TR + quad * 8];
            bf16x8 vf1 = *(const bf16x8*)&Vsc[(ct * 16 + l15) * TR + 32 + quad * 8];
#pragma unroll
            for (int qg = 0; qg < 2; qg++) {
                o[qg][ct] = __builtin_amdgcn_mfma_f32_16x16x32_bf16(vf0, pb[qg][0], o[qg][ct], 0, 0, 0);
                o[qg][ct] = __builtin_amdgcn_mfma_f32_16x16x32_bf16(vf1, pb[qg][1], o[qg][ct], 0, 0, 0);
            }
        }
        __builtin_amdgcn_s_setprio(0);

        cur ^= 1;
    }
    __syncthreads();   // protect union reuse (oT overlaps Ks/Vs)

    // l reduction over the 4 quads (kv partitions), once
#pragma unroll
    for (int qg = 0; qg < 2; qg++) {
        psum[qg] += __shfl_xor(psum[qg], 16);
        psum[qg] += __shfl_xor(psum[qg], 32);
    }

    // epilogue: normalize, transpose via LDS, coalesced store
#pragma unroll
    for (int qg = 0; qg < 2; qg++) {
        float inv = 1.0f / psum[qg];
#pragma unroll
        for (int ct = 0; ct < 4; ct++) {
            float4 vv;
            vv.x = o[qg][ct][0] * inv; vv.y = o[qg][ct][1] * inv;
            vv.z = o[qg][ct][2] * inv; vv.w = o[qg][ct][3] * inv;
            *(float4*)&u.oT[wave][qg][l15][ct * 16 + quad * 4] = vv;
        }
    }
    __builtin_amdgcn_wave_barrier();
    {
        int qq = lane >> 2, d0 = (lane & 3) * 16;
#pragma unroll
        for (int qg = 0; qg < 2; qg++) {
            int s_abs = qt * 128 + qg * 64 + wave * 16 + qq;
            float* dst = out + ((size_t)b * S_ + s_abs) * (H_ * D_) + h * D_ + d0;
#pragma unroll
            for (int j = 0; j < 4; j++) {
                float4 vj = *(float4*)&u.oT[wave][qg][qq][d0 + j * 4];
                *(float4*)(dst + j * 4) = vj;
            }
        }
    }
}

// ---------------------------------------------------------------------------
extern "C" void kernel_launch(void* const* d_in, const int* in_sizes, int n_in,
                              void* d_out, int out_size, void* d_ws, size_t ws_size,
                              hipStream_t stream)
{
    const float* X    = (const float*)d_in[0];
    const float* Wq   = (const float*)d_in[1];
    const float* bq   = (const float*)d_in[2];
    const float* Wk   = (const float*)d_in[3];
    const float* bk   = (const float*)d_in[4];
    const float* Wv   = (const float*)d_in[5];
    const float* bv   = (const float*)d_in[6];
    const float* mask = (const float*)d_in[7];

    char* ws = (char*)d_ws;
    unsigned short* Xb = (unsigned short*)(ws);                      // 16 MB (reused as Vt)
    unsigned short* Wt = (unsigned short*)(ws + 16777216);           //  6 MB
    unsigned short* Qb = (unsigned short*)(ws + 23068672);           // 16 MB
    unsigned short* Kb = (unsigned short*)(ws + 39845888);           // 16 MB
    unsigned short* Vb = (unsigned short*)(ws + 56623104);           // 16 MB
    unsigned short* Vt = Xb;   // Xb dead after qkv_gemm; reuse for V^T

    float* tab = (float*)d_out;   // RoPE tables in ctx region (overwritten by attn)

    rope_table_kernel<<<dim3(131072 / 256), 256, 0, stream>>>(tab);
    cast_x_kernel<<<dim3(M_ * HID / 4 / 256), 256, 0, stream>>>(X, Xb);
    cast_wt_kernel<<<dim3(16, 16, 3), 256, 0, stream>>>(Wq, Wk, Wv, Wt);
    qkv_gemm_kernel<<<dim3(HID / BN, M_ / BM, 3), 256, 0, stream>>>(
        Xb, Wt, bq, bk, bv, tab, tab + 131072, (float*)d_out, Qb, Kb, Vb);
    transpose_v_kernel<<<dim3(S_ / 64, B_ * H_), 256, 0, stream>>>(Vb, Vt);
    attn_kernel<<<dim3(H_, S_ / 128, B_), 256, 0, stream>>>(
        Qb, Kb, Vt, mask, (float*)d_out);
}

// Round 8
// 360.994 us; speedup vs baseline: 1.0869x; 1.0302x over previous
//
#include <hip/hip_runtime.h>

// ---------------------------------------------------------------------------
// MultiHeadsAttention: X[4,2048,1024] -> ctx[4,2048,1024], q[4,16,2048,64],
// k[4,16,2048,64] (q,k post-RoPE). fp32 in/out, bf16 MFMA internally.
// Round 16: R15's counted-vmcnt was NULL (124us unchanged) -> the qkv stall
// is not the load drain; three overlap variants (R11/R13/R15) all plateau
// at ~124us => per-ITERATION lockstep overhead is the candidate floor
// (~3.5k cy/iter observed vs ~400cy modeled compute). Test: BK=64 as two
// 32-col sub-tiles (same 64B row stride -> same bank behavior, no swizzle),
// halving iterations 32->16 and barriers 64->32, doubling MFMA per barrier.
// LDS 16->32KB (R15 measured: 32KB does not cost occupancy at VGPR~84).
// Also: fuse rope+cast_x+cast_wt into ONE prep kernel (blockIdx-partitioned)
// to cut two launch gaps. attn frozen (R12 structure, ~122us).
// ---------------------------------------------------------------------------

#define B_  4
#define S_  2048
#define H_  16
#define D_  64
#define HID 1024
#define M_  (B_ * S_)          // 8192

typedef __attribute__((ext_vector_type(8))) short    bf16x8;
typedef __attribute__((ext_vector_type(4))) float    f32x4;
typedef __attribute__((ext_vector_type(4))) unsigned short u16x4;
typedef __attribute__((ext_vector_type(8))) unsigned short u16x8;
typedef __attribute__((ext_vector_type(2))) unsigned u32x2;

__device__ __forceinline__ unsigned short f2bf(float f) {
    union { float f; unsigned u; } v; v.f = f;
    unsigned r = v.u + 0x7fffu + ((v.u >> 16) & 1u);
    return (unsigned short)(r >> 16);
}

__device__ __forceinline__ void async16(const unsigned short* g, unsigned short* l) {
    __builtin_amdgcn_global_load_lds(
        (const __attribute__((address_space(1))) void*)g,
        (__attribute__((address_space(3))) void*)l, 16, 0, 0);
}

__device__ __forceinline__ float fast_exp2(float x) {
    float r;
    asm("v_exp_f32 %0, %1" : "=v"(r) : "v"(x));
    return r;
}

// ---------------------------------------------------------------------------
// Kernel P: fused prep — blockIdx-partitioned:
//   [0, 8192)        cast_x  : X fp32 -> Xb bf16
//   [8192, 8704)     rope    : cos/sin tables -> tab
//   [8704, 9472)     cast_wt : W[k][n] fp32 -> Wt[n][k] bf16 (z = q/k/v)
// ---------------------------------------------------------------------------
__global__ __launch_bounds__(256) void prep_kernel(
    const float* __restrict__ X, unsigned short* __restrict__ Xb,
    const float* __restrict__ Wq, const float* __restrict__ Wk,
    const float* __restrict__ Wv, unsigned short* __restrict__ Wt,
    float* __restrict__ tab)
{
    __shared__ float tile[64][65];     // used by cast_wt branch only
    int blk = blockIdx.x;
    int tid = threadIdx.x;

    if (blk < 8192) {                  // ---- cast_x
        int i = (blk * 256 + tid) * 4;
        float4 v = *(const float4*)(X + i);
        u16x4 o;
        o[0] = f2bf(v.x); o[1] = f2bf(v.y); o[2] = f2bf(v.z); o[3] = f2bf(v.w);
        *(u16x4*)(Xb + i) = o;
    } else if (blk < 8704) {           // ---- rope tables
        int i = (blk - 8192) * 256 + tid;      // 0 .. 131071
        int s = i >> 6, d = i & 63;
        const float NEG_LN1E4_32 = -0.28782313662425576f;  // -ln(10000)/32
        float freq = __expf(NEG_LN1E4_32 * (float)(d >> 1));
        float ang = (float)s * freq;
        tab[i]          = cosf(ang);
        tab[131072 + i] = sinf(ang);
    } else {                           // ---- cast_wt (768 blocks)
        int idx = blk - 8704;
        int x = idx & 15, y = (idx >> 4) & 15, z = idx >> 8;
        const float* W = (z == 0) ? Wq : ((z == 1) ? Wk : Wv);
        unsigned short* out = Wt + (size_t)z * HID * HID;
        int n0 = x * 64, k0 = y * 64;
        int tx = tid & 63, ty0 = tid >> 6;
#pragma unroll
        for (int i = 0; i < 16; i++) {
            int ty = ty0 * 16 + i;
            tile[ty][tx] = W[(size_t)(k0 + ty) * HID + n0 + tx];
        }
        __syncthreads();
#pragma unroll
        for (int i = 0; i < 16; i++) {
            int ty = ty0 * 16 + i;
            out[(size_t)(n0 + ty) * HID + k0 + tx] = f2bf(tile[tx][ty]);
        }
    }
}

// ---------------------------------------------------------------------------
// Kernel 3: QKV GEMM, 128x128 tile, BK=64 as two 32-col sub-tiles,
// global_load_lds staging, 4 waves each 64x64. Bias + table-RoPE epilogue.
// 16 iterations, 2 barriers each (was 32x2). Row stride stays 64B ->
// same bank-conflict behavior as BK=32.
// ---------------------------------------------------------------------------
#define BM 128
#define BN 128

__global__ __launch_bounds__(256) void qkv_gemm_kernel(
    const unsigned short* __restrict__ Xb, const unsigned short* __restrict__ Wt,
    const float* __restrict__ bq, const float* __restrict__ bk,
    const float* __restrict__ bv,
    const float* __restrict__ cosT, const float* __restrict__ sinT,
    float* out,
    unsigned short* __restrict__ Qb, unsigned short* __restrict__ Kb,
    unsigned short* __restrict__ Vb)
{
    __shared__ unsigned short As[2][BM * 32];   // two 8KB col-half sub-tiles
    __shared__ unsigned short Bs[2][BN * 32];   // two 8KB

    const size_t Q_OFF = (size_t)B_ * S_ * HID;
    const size_t K_OFF = 2 * Q_OFF;

    int z = blockIdx.z;
    const unsigned short* W = Wt + (size_t)z * HID * HID;
    const float* bias = (z == 0) ? bq : ((z == 1) ? bk : bv);

    int n0 = blockIdx.x * BN, m0 = blockIdx.y * BM;
    int tid = threadIdx.x;
    int wave = tid >> 6, lane = tid & 63;
    int quad = lane >> 4, l15 = lane & 15;
    int wm = (wave >> 1) * 64;
    int wn = (wave & 1) * 64;

    const unsigned short* Ag = Xb + (size_t)m0 * HID;
    const unsigned short* Bg = W  + (size_t)n0 * HID;

    int e0 = tid, e1 = 256 + tid;
    int r0 = e0 >> 2, c0 = (e0 & 3) * 8;
    int r1 = e1 >> 2, c1 = (e1 & 3) * 8;

    f32x4 acc[4][4] = {};

    for (int k0 = 0; k0 < HID; k0 += 64) {
        // stage both 32-col halves of the 64-wide K-slab (8 async16/thread)
        async16(Ag + (size_t)r0 * HID + k0 + c0,      &As[0][e0 * 8]);
        async16(Ag + (size_t)r1 * HID + k0 + c1,      &As[0][e1 * 8]);
        async16(Ag + (size_t)r0 * HID + k0 + 32 + c0, &As[1][e0 * 8]);
        async16(Ag + (size_t)r1 * HID + k0 + 32 + c1, &As[1][e1 * 8]);
        async16(Bg + (size_t)r0 * HID + k0 + c0,      &Bs[0][e0 * 8]);
        async16(Bg + (size_t)r1 * HID + k0 + c1,      &Bs[0][e1 * 8]);
        async16(Bg + (size_t)r0 * HID + k0 + 32 + c0, &Bs[1][e0 * 8]);
        async16(Bg + (size_t)r1 * HID + k0 + 32 + c1, &Bs[1][e1 * 8]);
        __syncthreads();

#pragma unroll
        for (int kk = 0; kk < 2; kk++) {
            bf16x8 af[4], bf[4];
#pragma unroll
            for (int t = 0; t < 4; t++)
                af[t] = *(const bf16x8*)&As[kk][(wm + t * 16 + l15) * 32 + quad * 8];
#pragma unroll
            for (int t = 0; t < 4; t++)
                bf[t] = *(const bf16x8*)&Bs[kk][(wn + t * 16 + l15) * 32 + quad * 8];
#pragma unroll
            for (int rt = 0; rt < 4; rt++)
#pragma unroll
                for (int ct = 0; ct < 4; ct++)
                    acc[rt][ct] = __builtin_amdgcn_mfma_f32_16x16x32_bf16(
                        af[rt], bf[ct], acc[rt][ct], 0, 0, 0);
        }
        __syncthreads();
    }

    // epilogue: C/D layout col = l15, row = quad*4 + r
#pragma unroll
    for (int ct = 0; ct < 4; ct++) {
        int n = n0 + wn + ct * 16 + l15;
        float bval = bias[n];
        int h = n >> 6, d = n & 63;
#pragma unroll
        for (int rt = 0; rt < 4; rt++) {
#pragma unroll
            for (int r = 0; r < 4; r++) {
                int m = m0 + wm + rt * 16 + quad * 4 + r;
                int b = m >> 11, s = m & (S_ - 1);
                float y = acc[rt][ct][r] + bval;
                size_t o = ((size_t)(b * H_ + h) * S_ + s) * D_ + d;
                if (z < 2) {
                    float c  = cosT[s * 64 + d];
                    float sn = sinT[s * 64 + d];
                    float p = __shfl_xor(y, 1);
                    float yr = ((d & 1) == 0) ? (y * c - p * sn) : (y * c + p * sn);
                    if (z == 0) { out[Q_OFF + o] = yr; Qb[o] = f2bf(yr); }
                    else        { out[K_OFF + o] = yr; Kb[o] = f2bf(yr); }
                } else {
                    Vb[o] = f2bf(y);
                }
            }
        }
    }
}

// ---------------------------------------------------------------------------
// Kernel 3b: transpose V: Vb[bh][s][d] -> Vt[bh][d][s]
// ---------------------------------------------------------------------------
__global__ __launch_bounds__(256) void transpose_v_kernel(
    const unsigned short* __restrict__ Vb, unsigned short* __restrict__ Vt)
{
    __shared__ unsigned short t[64][72];
    int bh = blockIdx.y;
    int s0 = blockIdx.x * 64;
    const unsigned short* src = Vb + ((size_t)bh * S_ + s0) * D_;
    unsigned short* dst = Vt + (size_t)bh * D_ * S_;
    int tid = threadIdx.x;
#pragma unroll
    for (int i = 0; i < 2; i++) {
        int e = i * 256 + tid;
        int row = e >> 3, c = (e & 7) * 8;
        u16x8 v = *(const u16x8*)(src + (size_t)row * D_ + c);
#pragma unroll
        for (int j = 0; j < 8; j++) t[row][c + j] = v[j];
    }
    __syncthreads();
#pragma unroll
    for (int i = 0; i < 2; i++) {
        int e = i * 256 + tid;
        int d = e >> 3, sc = (e & 7) * 8;
        u16x8 v;
#pragma unroll
        for (int j = 0; j < 8; j++) v[j] = t[sc + j][d];
        *(u16x8*)(dst + (size_t)d * S_ + s0 + sc) = v;
    }
}

// ---------------------------------------------------------------------------
// Kernel 4: flash attention (frozen — R12 structure, ~122us warm).
// K/V double-buffered in padded LDS (TR=72), ONE barrier per kv-tile.
// P^T in registers via cvt_pk + permlane butterfly; exp via v_exp_f32.
// ---------------------------------------------------------------------------
#define TR 72          // padded tile row, u16

__global__ __launch_bounds__(256, 4) void attn_kernel(
    const unsigned short* __restrict__ Qb, const unsigned short* __restrict__ Kb,
    const unsigned short* __restrict__ Vt, const float* __restrict__ mask,
    float* __restrict__ out)
{
    __shared__ union {
        struct {
            unsigned short Ks[2][64 * TR];     // 18432 B
            unsigned short Vs[2][64 * TR];     // 18432 B
        } s;                                    // 36864 B
        float oT[4][2][16][68];                 // 34816 B (epilogue)
    } u;

    int h  = blockIdx.x;
    int qt = blockIdx.y;
    int b  = blockIdx.z;
    int tid = threadIdx.x;
    int wave = tid >> 6, lane = tid & 63;
    int quad = lane >> 4, l15 = lane & 15;

    size_t bh = (size_t)(b * H_ + h);
    const unsigned short* Qp = Qb + bh * S_ * D_;
    const unsigned short* Kp = Kb + bh * S_ * D_;
    const unsigned short* Vp = Vt + bh * D_ * S_;
    const float* mp = mask + (size_t)b * S_;

    // Q B-frags (n=q, k=d), held in registers for the whole loop
    bf16x8 qb[2][2];
#pragma unroll
    for (int qg = 0; qg < 2; qg++)
#pragma unroll
        for (int hf = 0; hf < 2; hf++) {
            int qrow = qt * 128 + qg * 64 + wave * 16 + l15;
            qb[qg][hf] = *(const bf16x8*)(Qp + (size_t)qrow * D_ + hf * 32 + quad * 8);
        }

    f32x4 o[2][4] = {};
    float psum[2] = {0.0f, 0.0f};
    const float C2    = 0.03125f * 1.44269504f;   // (1/sqrt(1024)) * log2(e)
    const float LOG2E = 1.44269504f;

    // staging granules: rows 0..31 (e=tid) and 32..63 (e=tid+256); same col
    int sr0 = tid >> 3, sg0 = (tid & 7) * 8;
    int sr1 = sr0 + 32;

    // prologue: load tile 0 into regs
    u16x8 kr0 = *(const u16x8*)(Kp + (size_t)sr0 * D_ + sg0);
    u16x8 kr1 = *(const u16x8*)(Kp + (size_t)sr1 * D_ + sg0);
    u16x8 vr0 = *(const u16x8*)(Vp + (size_t)sr0 * S_ + sg0);
    u16x8 vr1 = *(const u16x8*)(Vp + (size_t)sr1 * S_ + sg0);

    int cur = 0;
    for (int kv0 = 0; kv0 < S_; kv0 += 64) {
        // stage current tile into buf[cur] (vmcnt drain happens here)
        *(u16x8*)&u.s.Ks[cur][sr0 * TR + sg0] = kr0;
        *(u16x8*)&u.s.Ks[cur][sr1 * TR + sg0] = kr1;
        *(u16x8*)&u.s.Vs[cur][sr0 * TR + sg0] = vr0;
        *(u16x8*)&u.s.Vs[cur][sr1 * TR + sg0] = vr1;
        __syncthreads();

        // issue next tile's global loads (drain overlaps compute below)
        int kvn = (kv0 + 64 < S_) ? kv0 + 64 : 0;
        kr0 = *(const u16x8*)(Kp + (size_t)(kvn + sr0) * D_ + sg0);
        kr1 = *(const u16x8*)(Kp + (size_t)(kvn + sr1) * D_ + sg0);
        vr0 = *(const u16x8*)(Vp + (size_t)sr0 * S_ + kvn + sg0);
        vr1 = *(const u16x8*)(Vp + (size_t)sr1 * S_ + kvn + sg0);

        const unsigned short* Ksc = u.s.Ks[cur];
        const unsigned short* Vsc = u.s.Vs[cur];

        // S^T: A = K rows (m=kv), B = Q (n=q); K-frags shared across q-groups
        f32x4 sa[2][4] = {};
        __builtin_amdgcn_s_setprio(1);
#pragma unroll
        for (int mt = 0; mt < 4; mt++) {
            bf16x8 kf0 = *(const bf16x8*)&Ksc[(mt * 16 + l15) * TR + quad * 8];
            bf16x8 kf1 = *(const bf16x8*)&Ksc[(mt * 16 + l15) * TR + 32 + quad * 8];
#pragma unroll
            for (int qg = 0; qg < 2; qg++) {
                sa[qg][mt] = __builtin_amdgcn_mfma_f32_16x16x32_bf16(kf0, qb[qg][0], sa[qg][mt], 0, 0, 0);
                sa[qg][mt] = __builtin_amdgcn_mfma_f32_16x16x32_bf16(kf1, qb[qg][1], sa[qg][mt], 0, 0, 0);
            }
        }
        __builtin_amdgcn_s_setprio(0);

        // p = exp2(s*C2 + mask*log2e); pack pairs to bf16 in-register
        unsigned pw[2][4][2];
#pragma unroll
        for (int mt = 0; mt < 4; mt++) {
            f32x4 mkv = *(const f32x4*)(mp + kv0 + mt * 16 + quad * 4);
#pragma unroll
            for (int qg = 0; qg < 2; qg++) {
                f32x4 pv;
#pragma unroll
                for (int r = 0; r < 4; r++)
                    pv[r] = fast_exp2(sa[qg][mt][r] * C2 + mkv[r] * LOG2E);
                psum[qg] += (pv[0] + pv[1]) + (pv[2] + pv[3]);
                asm("v_cvt_pk_bf16_f32 %0, %1, %2"
                    : "=v"(pw[qg][mt][0]) : "v"(pv[0]), "v"(pv[1]));
                asm("v_cvt_pk_bf16_f32 %0, %1, %2"
                    : "=v"(pw[qg][mt][1]) : "v"(pv[2]), "v"(pv[3]));
            }
        }

        // quad butterfly: pw[qg][mt][t] (lane qs holds kv=mt*16+qs*4+2t,+1)
        // -> pb[qg][hf] word t' = P^T[q=l15][kv=hf*32+quad*8+2t',+1]
        bf16x8 pb[2][2];
#pragma unroll
        for (int qg = 0; qg < 2; qg++)
#pragma unroll
            for (int hf = 0; hf < 2; hf++) {
                union { unsigned w[4]; bf16x8 v; } pbu;
#pragma unroll
                for (int t = 0; t < 2; t++) {
                    unsigned A = pw[qg][2 * hf + 0][t];
                    unsigned B = pw[qg][2 * hf + 1][t];
                    u32x2 r1 = __builtin_amdgcn_permlane32_swap(A, B, false, false);
                    u32x2 r2 = __builtin_amdgcn_permlane16_swap(r1[0], r1[1], false, false);
                    pbu.w[t]     = r2[0];
                    pbu.w[2 + t] = r2[1];
                }
                pb[qg][hf] = pbu.v;
            }

        // PV: A = V^T rows (m=d), B = P^T in registers; V-frags shared
        __builtin_amdgcn_s_setprio(1);
#pragma unroll
        for (int ct = 0; ct < 4; ct++) {
            bf16x8 vf0 = *(const bf16x8*)&Vsc[(ct * 16 + l15) * TR + quad * 8];
            bf16x8 vf1 = *(const bf16x8*)&Vsc[(ct * 16 + l15) * TR + 32 + quad * 8];
#pragma unroll
            for (int qg = 0; qg < 2; qg++) {
                o[qg][ct] = __builtin_amdgcn_mfma_f32_16x16x32_bf16(vf0, pb[qg][0], o[qg][ct], 0, 0, 0);
                o[qg][ct] = __builtin_amdgcn_mfma_f32_16x16x32_bf16(vf1, pb[qg][1], o[qg][ct], 0, 0, 0);
            }
        }
        __builtin_amdgcn_s_setprio(0);

        cur ^= 1;
    }
    __syncthreads();   // protect union reuse (oT overlaps Ks/Vs)

    // l reduction over the 4 quads (kv partitions), once
#pragma unroll
    for (int qg = 0; qg < 2; qg++) {
        psum[qg] += __shfl_xor(psum[qg], 16);
        psum[qg] += __shfl_xor(psum[qg], 32);
    }

    // epilogue: normalize, transpose via LDS, coalesced store
#pragma unroll
    for (int qg = 0; qg < 2; qg++) {
        float inv = 1.0f / psum[qg];
#pragma unroll
        for (int ct = 0; ct < 4; ct++) {
            float4 vv;
            vv.x = o[qg][ct][0] * inv; vv.y = o[qg][ct][1] * inv;
            vv.z = o[qg][ct][2] * inv; vv.w = o[qg][ct][3] * inv;
            *(float4*)&u.oT[wave][qg][l15][ct * 16 + quad * 4] = vv;
        }
    }
    __builtin_amdgcn_wave_barrier();
    {
        int qq = lane >> 2, d0 = (lane & 3) * 16;
#pragma unroll
        for (int qg = 0; qg < 2; qg++) {
            int s_abs = qt * 128 + qg * 64 + wave * 16 + qq;
            float* dst = out + ((size_t)b * S_ + s_abs) * (H_ * D_) + h * D_ + d0;
#pragma unroll
            for (int j = 0; j < 4; j++) {
                float4 vj = *(float4*)&u.oT[wave][qg][qq][d0 + j * 4];
                *(float4*)(dst + j * 4) = vj;
            }
        }
    }
}

// ---------------------------------------------------------------------------
extern "C" void kernel_launch(void* const* d_in, const int* in_sizes, int n_in,
                              void* d_out, int out_size, void* d_ws, size_t ws_size,
                              hipStream_t stream)
{
    const float* X    = (const float*)d_in[0];
    const float* Wq   = (const float*)d_in[1];
    const float* bq   = (const float*)d_in[2];
    const float* Wk   = (const float*)d_in[3];
    const float* bk   = (const float*)d_in[4];
    const float* Wv   = (const float*)d_in[5];
    const float* bv   = (const float*)d_in[6];
    const float* mask = (const float*)d_in[7];

    char* ws = (char*)d_ws;
    unsigned short* Xb = (unsigned short*)(ws);                      // 16 MB (reused as Vt)
    unsigned short* Wt = (unsigned short*)(ws + 16777216);           //  6 MB
    unsigned short* Qb = (unsigned short*)(ws + 23068672);           // 16 MB
    unsigned short* Kb = (unsigned short*)(ws + 39845888);           // 16 MB
    unsigned short* Vb = (unsigned short*)(ws + 56623104);           // 16 MB
    unsigned short* Vt = Xb;   // Xb dead after qkv_gemm; reuse for V^T

    float* tab = (float*)d_out;   // RoPE tables in ctx region (overwritten by attn)

    prep_kernel<<<dim3(9472), 256, 0, stream>>>(X, Xb, Wq, Wk, Wv, Wt, tab);
    qkv_gemm_kernel<<<dim3(HID / BN, M_ / BM, 3), 256, 0, stream>>>(
        Xb, Wt, bq, bk, bv, tab, tab + 131072, (float*)d_out, Qb, Kb, Vb);
    transpose_v_kernel<<<dim3(S_ / 64, B_ * H_), 256, 0, stream>>>(Vb, Vt);
    attn_kernel<<<dim3(H_, S_ / 128, B_), 256, 0, stream>>>(
        Qb, Kb, Vt, mask, (float*)d_out);
}